// Round 1
// baseline (320.694 us; speedup 1.0000x reference)
//
#include <hip/hip_runtime.h>

typedef short s16x8 __attribute__((ext_vector_type(8)));
typedef float f32x4 __attribute__((ext_vector_type(4)));
typedef float f32x2 __attribute__((ext_vector_type(2)));

#define TILE 2048  // edges per block in binning passes (256 thr x 8)

// ---------- bf16 helpers (bit-level, RNE) ----------
__device__ __forceinline__ unsigned int brne(float f) {
    unsigned int u = __float_as_uint(f);
    return (u + 0x7FFFu + ((u >> 16) & 1u)) >> 16;   // bf16 bits in low 16
}
__device__ __forceinline__ float blo(unsigned int u) { return __uint_as_float(u << 16); }
__device__ __forceinline__ float bhi(unsigned int u) { return __uint_as_float(u & 0xFFFF0000u); }

// accumulate 8 bf16 lanes of a uint4 row piece, scaled by wt
__device__ __forceinline__ void acc8(float* a, const uint4 u, const float wt) {
    a[0] += blo(u.x) * wt; a[1] += bhi(u.x) * wt;
    a[2] += blo(u.y) * wt; a[3] += bhi(u.y) * wt;
    a[4] += blo(u.z) * wt; a[5] += bhi(u.z) * wt;
    a[6] += blo(u.w) * wt; a[7] += bhi(u.w) * wt;
}

// ---------- fp8 e4m3 (OCP) helpers via HW cvt ----------
__device__ __forceinline__ unsigned int enc_fp8(float v) {
    return __builtin_amdgcn_cvt_pk_fp8_f32(v, v, 0, false) & 0xFF;
}
// packed accumulate: 16 fp8 of a uint4 into 8 f32x2 accumulators (v_pk_fma path)
__device__ __forceinline__ void acc16p(f32x2* a, const uint4 u, const f32x2 w2) {
    a[0] += __builtin_amdgcn_cvt_pk_f32_fp8((int)u.x, false) * w2;
    a[1] += __builtin_amdgcn_cvt_pk_f32_fp8((int)u.x, true)  * w2;
    a[2] += __builtin_amdgcn_cvt_pk_f32_fp8((int)u.y, false) * w2;
    a[3] += __builtin_amdgcn_cvt_pk_f32_fp8((int)u.y, true)  * w2;
    a[4] += __builtin_amdgcn_cvt_pk_f32_fp8((int)u.z, false) * w2;
    a[5] += __builtin_amdgcn_cvt_pk_f32_fp8((int)u.z, true)  * w2;
    a[6] += __builtin_amdgcn_cvt_pk_f32_fp8((int)u.w, false) * w2;
    a[7] += __builtin_amdgcn_cvt_pk_f32_fp8((int)u.w, true)  * w2;
}

// ---------------- binned CSR build ----------------
// bucket = dst >> 8 (256 nodes per bucket); bucket b <-> nodes [b*256,b*256+255]

__global__ void k_bhist(const int* __restrict__ dst, int* __restrict__ bucket_cnt,
                        int e, int nb) {
    __shared__ int h[256];
    const int tid = threadIdx.x;
    h[tid] = 0;
    __syncthreads();
    const int base = blockIdx.x * TILE + tid;
#pragma unroll
    for (int k = 0; k < 8; k++) {
        const int i = base + k * 256;
        if (i < e) atomicAdd(&h[dst[i] >> 8], 1);
    }
    __syncthreads();
    if (tid < nb && h[tid]) atomicAdd(&bucket_cnt[tid], h[tid]);
}

__global__ void k_bscan(const int* __restrict__ bucket_cnt, int* __restrict__ bucket_base,
                        int* __restrict__ bucket_cursor, int nb, int e) {
    __shared__ int sh[256];
    const int tid = threadIdx.x;
    const int v = (tid < nb) ? bucket_cnt[tid] : 0;
    int x = v;
    sh[tid] = x;
    __syncthreads();
    for (int off = 1; off < 256; off <<= 1) {
        const int t = (tid >= off) ? sh[tid - off] : 0;
        __syncthreads();
        if (tid >= off) { x += t; sh[tid] = x; }
        __syncthreads();
    }
    if (tid < nb) { bucket_base[tid] = x - v; bucket_cursor[tid] = x - v; }
    if (tid == 0) bucket_base[nb] = e;
}

__global__ void k_bscatter(const int* __restrict__ src, const int* __restrict__ dst,
                           int* __restrict__ bucket_cursor, uint2* __restrict__ eb, int e) {
    __shared__ int h[256], hbase[256], h2[256];
    const int tid = threadIdx.x;
    h[tid] = 0; h2[tid] = 0;
    __syncthreads();
    const int base = blockIdx.x * TILE + tid;
    int s[8], d[8], b[8];
    bool val[8];
#pragma unroll
    for (int k = 0; k < 8; k++) {
        const int i = base + k * 256;
        val[k] = i < e;
        if (val[k]) {
            s[k] = src[i]; d[k] = dst[i]; b[k] = d[k] >> 8;
            atomicAdd(&h[b[k]], 1);
        }
    }
    __syncthreads();
    if (h[tid]) hbase[tid] = atomicAdd(&bucket_cursor[tid], h[tid]);
    __syncthreads();
#pragma unroll
    for (int k = 0; k < 8; k++) {
        if (val[k]) {
            const int off = atomicAdd(&h2[b[k]], 1);
            eb[hbase[b[k]] + off] = make_uint2((unsigned)s[k], (unsigned)d[k]);
        }
    }
}

// fused: per-bucket exact node histogram + dinv + block-local exclusive scan
// (rowptr holds LOCAL offsets after this; part[b] = bucket total)
__global__ void k_nhist_scan(const uint2* __restrict__ eb, const int* __restrict__ bucket_base,
                             int* __restrict__ rowptr, int* __restrict__ part,
                             float* __restrict__ dinv, int n) {
    __shared__ int c[256], sh[256];
    const int tid = threadIdx.x, b = blockIdx.x;
    c[tid] = 0;
    __syncthreads();
    const int beg = bucket_base[b], end = bucket_base[b + 1];
    for (int i = beg + tid; i < end; i += 256)
        atomicAdd(&c[eb[i].y & 255], 1);
    __syncthreads();
    const int v = c[tid];
    const int node = b * 256 + tid;
    if (node < n) dinv[node] = rsqrtf((float)(v + 1));  // deg includes self-loop
    int x = v;
    sh[tid] = x;
    __syncthreads();
    for (int off = 1; off < 256; off <<= 1) {
        const int t = (tid >= off) ? sh[tid - off] : 0;
        __syncthreads();
        if (tid >= off) { x += t; sh[tid] = x; }
        __syncthreads();
    }
    if (node <= n) rowptr[node] = x - v;       // local exclusive offset
    if (tid == 255) part[b] = x;               // bucket total
}

// fused: part-prefix (scan2) + rowptr globalization (scan3) + placement
__global__ void k_place(const uint2* __restrict__ eb, const int* __restrict__ bucket_base,
                        int* __restrict__ rowptr, const int* __restrict__ part,
                        int* __restrict__ es, int n, int nb) {
    __shared__ int sh[256], rp[256], offs[256];
    const int tid = threadIdx.x, b = blockIdx.x;
    // inclusive scan of part[] (196 entries)
    int x = (tid < nb) ? part[tid] : 0;
    sh[tid] = x;
    __syncthreads();
    for (int off = 1; off < 256; off <<= 1) {
        const int t = (tid >= off) ? sh[tid - off] : 0;
        __syncthreads();
        if (tid >= off) { x += t; sh[tid] = x; }
        __syncthreads();
    }
    const int prefix = (b > 0) ? sh[b - 1] : 0;
    const int node = b * 256 + tid;
    int rg = 0;
    if (node <= n) {
        rg = rowptr[node] + prefix;
        rowptr[node] = rg;                     // now global (props read this)
    }
    rp[tid] = rg;
    offs[tid] = 0;
    __syncthreads();
    const int beg = bucket_base[b], end = bucket_base[b + 1];
    for (int i = beg + tid; i < end; i += 256) {
        const uint2 ed = eb[i];
        const int d = (int)ed.y & 255;
        const int local = atomicAdd(&offs[d], 1);
        es[rp[d] + local] = (int)ed.x;
    }
}

// ---------------- dtype prep: both weight transposes in one kernel ----------------
// W1[K=256][256] -> W1t[256][256]; W2[K=256][128] -> W2t[128][256]
__global__ void k_tW2(const float* __restrict__ W1, const float* __restrict__ W2,
                      unsigned short* __restrict__ W1t, unsigned short* __restrict__ W2t) {
    const int t = blockIdx.x * 256 + threadIdx.x;
    if (t < 65536) {
        const int k = t >> 8, nn = t & 255;
        W1t[nn * 256 + k] = (unsigned short)brne(W1[t]);
    } else {
        const int u = t - 65536;
        const int k = u >> 7, nn = u & 127;
        W2t[nn * 256 + k] = (unsigned short)brne(W2[u]);
    }
}

// ---------------- MFMA GEMM: C[M,Nc] = A[M,256] @ Bt[Nc,256]^T ----------------
// AF32: A is fp32 (cast to bf16 in staging)   FP8OUT: C quantized to fp8 e4m3
#define LP 40
template <bool AF32, bool FP8OUT>
__global__ __launch_bounds__(256) void k_gemm(const void* __restrict__ Av,
                                              const unsigned short* __restrict__ Bt,
                                              void* __restrict__ Cout,
                                              int M, int Nc) {
    __shared__ unsigned short As[128 * LP];
    __shared__ unsigned short Bs[128 * LP];

    const int tid = threadIdx.x;
    const int wave = tid >> 6, lane = tid & 63;
    const int wm = (wave >> 1) * 64, wn = (wave & 1) * 64;
    const int l15 = lane & 15, quad = lane >> 4;
    const int mBase = blockIdx.x * 128, nBase = blockIdx.y * 128;

    f32x4 acc[4][4];
#pragma unroll
    for (int i = 0; i < 4; i++)
#pragma unroll
        for (int j = 0; j < 4; j++) acc[i][j] = (f32x4){0.f, 0.f, 0.f, 0.f};

    const int r0 = tid >> 2, kc0 = tid & 3;       // staged rows r0 and r0+64
    int am0 = mBase + r0;      if (am0 >= M) am0 = M - 1;
    int am1 = mBase + r0 + 64; if (am1 >= M) am1 = M - 1;

    const uint4* Ap0; const uint4* Ap1; const float4* Af0; const float4* Af1;
    if (AF32) {
        Af0 = (const float4*)Av + (size_t)am0 * 64 + kc0 * 2;
        Af1 = (const float4*)Av + (size_t)am1 * 64 + kc0 * 2;
    } else {
        Ap0 = (const uint4*)Av + (size_t)am0 * 32 + kc0;
        Ap1 = (const uint4*)Av + (size_t)am1 * 32 + kc0;
    }
    const uint4* Bp0 = (const uint4*)Bt + (size_t)(nBase + r0) * 32 + kc0;
    const uint4* Bp1 = (const uint4*)Bt + (size_t)(nBase + r0 + 64) * 32 + kc0;

    for (int kt = 0; kt < 8; ++kt) {
        uint4 a0, a1;
        if (AF32) {
            const float4 l0 = Af0[kt * 8], h0 = Af0[kt * 8 + 1];
            const float4 l1 = Af1[kt * 8], h1 = Af1[kt * 8 + 1];
            a0.x = brne(l0.x) | (brne(l0.y) << 16); a0.y = brne(l0.z) | (brne(l0.w) << 16);
            a0.z = brne(h0.x) | (brne(h0.y) << 16); a0.w = brne(h0.z) | (brne(h0.w) << 16);
            a1.x = brne(l1.x) | (brne(l1.y) << 16); a1.y = brne(l1.z) | (brne(l1.w) << 16);
            a1.z = brne(h1.x) | (brne(h1.y) << 16); a1.w = brne(h1.z) | (brne(h1.w) << 16);
        } else {
            a0 = Ap0[kt * 4];
            a1 = Ap1[kt * 4];
        }
        const uint4 b0 = Bp0[kt * 4];
        const uint4 b1 = Bp1[kt * 4];
        __syncthreads();
        *(uint4*)&As[r0 * LP + kc0 * 8] = a0;
        *(uint4*)&As[(r0 + 64) * LP + kc0 * 8] = a1;
        *(uint4*)&Bs[r0 * LP + kc0 * 8] = b0;
        *(uint4*)&Bs[(r0 + 64) * LP + kc0 * 8] = b1;
        __syncthreads();

        s16x8 af[4], bf[4];
#pragma unroll
        for (int i = 0; i < 4; i++)
            af[i] = *(const s16x8*)&As[(wm + i * 16 + l15) * LP + quad * 8];
#pragma unroll
        for (int j = 0; j < 4; j++)
            bf[j] = *(const s16x8*)&Bs[(wn + j * 16 + l15) * LP + quad * 8];
#pragma unroll
        for (int i = 0; i < 4; i++)
#pragma unroll
            for (int j = 0; j < 4; j++)
                acc[i][j] = __builtin_amdgcn_mfma_f32_16x16x32_bf16(af[i], bf[j], acc[i][j], 0, 0, 0);
    }

#pragma unroll
    for (int i = 0; i < 4; i++) {
        const int rowb = mBase + wm + i * 16 + quad * 4;
#pragma unroll
        for (int r = 0; r < 4; r++) {
            const int row = rowb + r;
            if (row < M) {
#pragma unroll
                for (int j = 0; j < 4; j++) {
                    const int col = nBase + wn + j * 16 + l15;
                    if (FP8OUT)
                        ((unsigned char*)Cout)[(size_t)row * Nc + col] =
                            (unsigned char)enc_fp8(acc[i][j][r]);
                    else
                        ((unsigned short*)Cout)[(size_t)row * Nc + col] =
                            (unsigned short)brne(acc[i][j][r]);
                }
            }
        }
    }
}

// ---------------- propagation ----------------
// L1: 256 feats fp8 = 16 uint4/row. Quarter-wave per edge -> 4 edges in
// flight; unroll 2 -> 8. Packed f32x2 accumulate (v_pk_fma). quad 0 stores H bf16.
// 2-stage software pipeline: edge indices + dinv weights are prefetched one
// iteration ahead so the per-iter dependent chain is only the row gather.
__global__ void k_prop256f8(const uint4* __restrict__ X4,
                            const int* __restrict__ rowptr,
                            const int* __restrict__ es,
                            const float* __restrict__ dinv,
                            const float* __restrict__ bias,
                            uint4* __restrict__ Y4, int n) {
    const int wid = (int)((blockIdx.x * blockDim.x + threadIdx.x) >> 6);
    const int lane = threadIdx.x & 63;
    const int quad = lane >> 4, l16 = lane & 15;
    if (wid >= n) return;
    const float dd = dinv[wid];
    f32x2 a[8];
#pragma unroll
    for (int k = 0; k < 8; k++) a[k] = (f32x2){0.f, 0.f};

    const int beg = rowptr[wid], end = rowptr[wid + 1];
    int j = beg + quad;
    // pipeline prologue: current indices + weights
    int sc0 = 0, sc1 = 0;
    float wc0 = 0.f, wc1 = 0.f;
    if (j < end)     { sc0 = es[j];     wc0 = dinv[sc0] * dd; }
    if (j + 4 < end) { sc1 = es[j + 4]; wc1 = dinv[sc1] * dd; }
    // self-loop: only quad 0 loads (exec-masked lanes fetch nothing)
    if (quad == 0) {
        const uint4 v = X4[(size_t)wid * 16 + l16];
        acc16p(a, v, (f32x2){dd * dd, dd * dd});
    }
    for (; j + 4 < end; j += 8) {
        // issue current rows first (addresses ready from previous iteration)
        const uint4 u0 = X4[(size_t)sc0 * 16 + l16];
        const uint4 u1 = X4[(size_t)sc1 * 16 + l16];
        // prefetch next indices (clamped -> branchless, always in-bounds:
        // loop body implies end >= j+5, so end-1 >= 4)
        const int jn0 = j + 8, jn1 = j + 12;
        const int sn0 = es[jn0 < end ? jn0 : end - 1];
        const int sn1 = es[jn1 < end ? jn1 : end - 1];
        const float wn0 = dinv[sn0] * dd, wn1 = dinv[sn1] * dd;
        acc16p(a, u0, (f32x2){wc0, wc0});
        acc16p(a, u1, (f32x2){wc1, wc1});
        sc0 = sn0; sc1 = sn1; wc0 = wn0; wc1 = wn1;
    }
    if (j < end) {  // at most one leftover edge per quad; sc0/wc0 hold es[j]
        const uint4 u0 = X4[(size_t)sc0 * 16 + l16];
        acc16p(a, u0, (f32x2){wc0, wc0});
    }
#pragma unroll
    for (int k = 0; k < 8; k++) {
        a[k][0] += __shfl_xor(a[k][0], 16);
        a[k][1] += __shfl_xor(a[k][1], 16);
        a[k][0] += __shfl_xor(a[k][0], 32);
        a[k][1] += __shfl_xor(a[k][1], 32);
    }
    if (quad == 0) {
        // feats linear order: a[0].xy, a[1].xy, ..., a[7].xy at base l16*16
        const float4* bp = (const float4*)bias + l16 * 4;
#pragma unroll
        for (int q = 0; q < 4; q++) {
            const float4 b = bp[q];
            a[2 * q][0]     = fmaxf(a[2 * q][0] + b.x, 0.f);
            a[2 * q][1]     = fmaxf(a[2 * q][1] + b.y, 0.f);
            a[2 * q + 1][0] = fmaxf(a[2 * q + 1][0] + b.z, 0.f);
            a[2 * q + 1][1] = fmaxf(a[2 * q + 1][1] + b.w, 0.f);
        }
        uint4 p0, p1;
        p0.x = brne(a[0][0]) | (brne(a[0][1]) << 16);
        p0.y = brne(a[1][0]) | (brne(a[1][1]) << 16);
        p0.z = brne(a[2][0]) | (brne(a[2][1]) << 16);
        p0.w = brne(a[3][0]) | (brne(a[3][1]) << 16);
        p1.x = brne(a[4][0]) | (brne(a[4][1]) << 16);
        p1.y = brne(a[5][0]) | (brne(a[5][1]) << 16);
        p1.z = brne(a[6][0]) | (brne(a[6][1]) << 16);
        p1.w = brne(a[7][0]) | (brne(a[7][1]) << 16);
        Y4[(size_t)wid * 32 + l16 * 2] = p0;
        Y4[(size_t)wid * 32 + l16 * 2 + 1] = p1;
    }
}

// L2: 128 feats bf16 = 16 uint4/row. Same pipelined structure; quad 0 stores fp32.
__global__ void k_prop128b(const uint4* __restrict__ X4,
                           const int* __restrict__ rowptr,
                           const int* __restrict__ es,
                           const float* __restrict__ dinv,
                           const float* __restrict__ bias,
                           float* __restrict__ Yout, int n) {
    const int wid = (int)((blockIdx.x * blockDim.x + threadIdx.x) >> 6);
    const int lane = threadIdx.x & 63;
    const int quad = lane >> 4, l16 = lane & 15;
    if (wid >= n) return;
    const float dd = dinv[wid];
    float a[8];
#pragma unroll
    for (int k = 0; k < 8; k++) a[k] = 0.f;

    const int beg = rowptr[wid], end = rowptr[wid + 1];
    int j = beg + quad;
    int sc0 = 0, sc1 = 0;
    float wc0 = 0.f, wc1 = 0.f;
    if (j < end)     { sc0 = es[j];     wc0 = dinv[sc0] * dd; }
    if (j + 4 < end) { sc1 = es[j + 4]; wc1 = dinv[sc1] * dd; }
    if (quad == 0) {
        const uint4 v = X4[(size_t)wid * 16 + l16];
        acc8(a, v, dd * dd);
    }
    for (; j + 4 < end; j += 8) {
        const uint4 u0 = X4[(size_t)sc0 * 16 + l16];
        const uint4 u1 = X4[(size_t)sc1 * 16 + l16];
        const int jn0 = j + 8, jn1 = j + 12;
        const int sn0 = es[jn0 < end ? jn0 : end - 1];
        const int sn1 = es[jn1 < end ? jn1 : end - 1];
        const float wn0 = dinv[sn0] * dd, wn1 = dinv[sn1] * dd;
        acc8(a, u0, wc0);
        acc8(a, u1, wc1);
        sc0 = sn0; sc1 = sn1; wc0 = wn0; wc1 = wn1;
    }
    if (j < end) {
        const uint4 u0 = X4[(size_t)sc0 * 16 + l16];
        acc8(a, u0, wc0);
    }
#pragma unroll
    for (int k = 0; k < 8; k++) {
        a[k] += __shfl_xor(a[k], 16);
        a[k] += __shfl_xor(a[k], 32);
    }
    if (quad == 0) {
        const float4 b0 = ((const float4*)bias)[l16 * 2];
        const float4 b1 = ((const float4*)bias)[l16 * 2 + 1];
        float4* op = (float4*)Yout + (size_t)wid * 32 + l16 * 2;
        op[0] = make_float4(a[0] + b0.x, a[1] + b0.y, a[2] + b0.z, a[3] + b0.w);
        op[1] = make_float4(a[4] + b1.x, a[5] + b1.y, a[6] + b1.z, a[7] + b1.w);
    }
}

extern "C" void kernel_launch(void* const* d_in, const int* in_sizes, int n_in,
                              void* d_out, int out_size, void* d_ws, size_t ws_size,
                              hipStream_t stream) {
    const float* x  = (const float*)d_in[0];
    const int*   ei = (const int*)d_in[1];
    const float* W1 = (const float*)d_in[2];
    const float* b1 = (const float*)d_in[3];
    const float* W2 = (const float*)d_in[4];
    const float* b2 = (const float*)d_in[5];
    float* out = (float*)d_out;

    const int n = in_sizes[0] / 256;  // 50000
    const int e = in_sizes[1] / 2;    // 1600000
    const int* src = ei;
    const int* dst = ei + e;
    const int nb = (n + 255) >> 8;    // 196 buckets (<=256 required)

    char* wsp = (char*)d_ws;
    size_t off = 0;
    auto alloc = [&](size_t bytes) -> char* {
        char* p = wsp + off;
        off += (bytes + 511) & ~(size_t)511;
        return p;
    };
    float* dinv    = (float*)alloc(sizeof(float) * n);
    int*   rowptr  = (int*)alloc(sizeof(int) * (n + 1));
    int*   part    = (int*)alloc(sizeof(int) * 256);
    int*   bcnt    = (int*)alloc(sizeof(int) * 256);
    int*   bbase   = (int*)alloc(sizeof(int) * 257);
    int*   bcur    = (int*)alloc(sizeof(int) * 256);
    int*   es      = (int*)alloc(sizeof(int) * e);
    unsigned short* W1t = (unsigned short*)alloc(2ull * 256 * 256); // [N][K]
    unsigned short* W2t = (unsigned short*)alloc(2ull * 128 * 256); // [N][K]
    unsigned char*  T1  = (unsigned char*)alloc((size_t)n * 256);   // x@W1 fp8
    unsigned short* H   = (unsigned short*)alloc(2ull * n * 256);   // relu(prop+b1) bf16
    unsigned short* T2  = (unsigned short*)alloc(2ull * n * 128);   // H@W2 bf16
    // eb (binned (src,dst) pairs, 8B*e = 12.8MB) aliases H (25.6MB):
    // build finishes (k_place) before H is first written (prop256f8).
    uint2* eb = (uint2*)H;

    const int nb_t = (e + TILE - 1) / TILE;

    // ---- binned CSR build (6 dispatches) ----
    (void)hipMemsetAsync(bcnt, 0, sizeof(int) * 256, stream);
    k_bhist<<<nb_t, 256, 0, stream>>>(dst, bcnt, e, nb);
    k_bscan<<<1, 256, 0, stream>>>(bcnt, bbase, bcur, nb, e);
    k_bscatter<<<nb_t, 256, 0, stream>>>(src, dst, bcur, eb, e);
    k_nhist_scan<<<nb, 256, 0, stream>>>(eb, bbase, rowptr, part, dinv, n);
    k_place<<<nb, 256, 0, stream>>>(eb, bbase, rowptr, part, es, n, nb);

    // ---- weights ----
    k_tW2<<<(65536 + 32768) / 256, 256, 0, stream>>>(W1, W2, W1t, W2t);

    // ---- layer 1: T1 = fp8(x@W1)  (fp32 A cast fused in staging) ----
    dim3 g1((n + 127) / 128, 2);
    k_gemm<true, true><<<g1, 256, 0, stream>>>(x, W1t, T1, n, 256);
    k_prop256f8<<<(n + 3) / 4, 256, 0, stream>>>((const uint4*)T1, rowptr, es,
                                                 dinv, b1, (uint4*)H, n);

    // ---- layer 2: T2 = bf16(H@W2); out = prop(T2)+b2 ----
    dim3 g2((n + 127) / 128, 1);
    k_gemm<false, false><<<g2, 256, 0, stream>>>(H, W2t, T2, n, 128);
    k_prop128b<<<(n + 3) / 4, 256, 0, stream>>>((const uint4*)T2, rowptr, es,
                                                dinv, b2, out, n);
}

// Round 2
// 317.112 us; speedup vs baseline: 1.0113x; 1.0113x over previous
//
#include <hip/hip_runtime.h>

typedef short s16x8 __attribute__((ext_vector_type(8)));
typedef float f32x4 __attribute__((ext_vector_type(4)));
typedef float f32x2 __attribute__((ext_vector_type(2)));

#define TILE 2048  // edges per block in binning passes (256 thr x 8)

// ---------- bf16 helpers (bit-level, RNE) ----------
__device__ __forceinline__ unsigned int brne(float f) {
    unsigned int u = __float_as_uint(f);
    return (u + 0x7FFFu + ((u >> 16) & 1u)) >> 16;   // bf16 bits in low 16
}
__device__ __forceinline__ float blo(unsigned int u) { return __uint_as_float(u << 16); }
__device__ __forceinline__ float bhi(unsigned int u) { return __uint_as_float(u & 0xFFFF0000u); }

// packed f32x2 -> bf16x2 via HW cvt (RNE), replaces 2x brne (~8 instrs) with 1
__device__ __forceinline__ unsigned int pk_bf16(float lo, float hi) {
    unsigned int r;
    asm("v_cvt_pk_bf16_f32 %0, %1, %2" : "=v"(r) : "v"(lo), "v"(hi));
    return r;
}

// accumulate 8 bf16 lanes of a uint4 row piece into 4 packed f32x2 (v_pk_fma)
__device__ __forceinline__ void acc8p(f32x2* a, const uint4 u, const f32x2 w2) {
    a[0] += (f32x2){blo(u.x), bhi(u.x)} * w2;
    a[1] += (f32x2){blo(u.y), bhi(u.y)} * w2;
    a[2] += (f32x2){blo(u.z), bhi(u.z)} * w2;
    a[3] += (f32x2){blo(u.w), bhi(u.w)} * w2;
}

// packed accumulate: 16 fp8 of a uint4 into 8 f32x2 accumulators (v_pk_fma path)
__device__ __forceinline__ void acc16p(f32x2* a, const uint4 u, const f32x2 w2) {
    a[0] += __builtin_amdgcn_cvt_pk_f32_fp8((int)u.x, false) * w2;
    a[1] += __builtin_amdgcn_cvt_pk_f32_fp8((int)u.x, true)  * w2;
    a[2] += __builtin_amdgcn_cvt_pk_f32_fp8((int)u.y, false) * w2;
    a[3] += __builtin_amdgcn_cvt_pk_f32_fp8((int)u.y, true)  * w2;
    a[4] += __builtin_amdgcn_cvt_pk_f32_fp8((int)u.z, false) * w2;
    a[5] += __builtin_amdgcn_cvt_pk_f32_fp8((int)u.z, true)  * w2;
    a[6] += __builtin_amdgcn_cvt_pk_f32_fp8((int)u.w, false) * w2;
    a[7] += __builtin_amdgcn_cvt_pk_f32_fp8((int)u.w, true)  * w2;
}

// ---------------- binned CSR build ----------------
// bucket = dst >> 8 (256 nodes per bucket); bucket b <-> nodes [b*256,b*256+255]

// fused: bucket histogram (blocks [0,nbt)) + weight transposes (blocks >= nbt)
__global__ void k_bhist_tw(const int* __restrict__ dst, int* __restrict__ bucket_cnt,
                           int e, int nb, int nbt,
                           const float* __restrict__ W1, const float* __restrict__ W2,
                           unsigned short* __restrict__ W1t, unsigned short* __restrict__ W2t) {
    const int tid = threadIdx.x;
    if ((int)blockIdx.x >= nbt) {
        const int t = ((int)blockIdx.x - nbt) * 256 + tid;
        if (t < 65536) {
            const int k = t >> 8, nn = t & 255;
            W1t[nn * 256 + k] = (unsigned short)brne(W1[t]);
        } else {
            const int u = t - 65536;
            const int k = u >> 7, nn = u & 127;
            W2t[nn * 256 + k] = (unsigned short)brne(W2[u]);
        }
        return;
    }
    __shared__ int h[256];
    h[tid] = 0;
    __syncthreads();
    const int base = blockIdx.x * TILE + tid;
#pragma unroll
    for (int k = 0; k < 8; k++) {
        const int i = base + k * 256;
        if (i < e) atomicAdd(&h[dst[i] >> 8], 1);
    }
    __syncthreads();
    if (tid < nb && h[tid]) atomicAdd(&bucket_cnt[tid], h[tid]);
}

__global__ void k_bscan(const int* __restrict__ bucket_cnt, int* __restrict__ bucket_base,
                        int* __restrict__ bucket_cursor, int nb, int e) {
    __shared__ int sh[256];
    const int tid = threadIdx.x;
    const int v = (tid < nb) ? bucket_cnt[tid] : 0;
    int x = v;
    sh[tid] = x;
    __syncthreads();
    for (int off = 1; off < 256; off <<= 1) {
        const int t = (tid >= off) ? sh[tid - off] : 0;
        __syncthreads();
        if (tid >= off) { x += t; sh[tid] = x; }
        __syncthreads();
    }
    if (tid < nb) { bucket_base[tid] = x - v; bucket_cursor[tid] = x - v; }
    if (tid == 0) bucket_base[nb] = e;
}

__global__ void k_bscatter(const int* __restrict__ src, const int* __restrict__ dst,
                           int* __restrict__ bucket_cursor, uint2* __restrict__ eb, int e) {
    __shared__ int h[256], hbase[256], h2[256];
    const int tid = threadIdx.x;
    h[tid] = 0; h2[tid] = 0;
    __syncthreads();
    const int base = blockIdx.x * TILE + tid;
    int s[8], d[8], b[8];
    bool val[8];
#pragma unroll
    for (int k = 0; k < 8; k++) {
        const int i = base + k * 256;
        val[k] = i < e;
        if (val[k]) {
            s[k] = src[i]; d[k] = dst[i]; b[k] = d[k] >> 8;
            atomicAdd(&h[b[k]], 1);
        }
    }
    __syncthreads();
    if (h[tid]) hbase[tid] = atomicAdd(&bucket_cursor[tid], h[tid]);
    __syncthreads();
#pragma unroll
    for (int k = 0; k < 8; k++) {
        if (val[k]) {
            const int off = atomicAdd(&h2[b[k]], 1);
            eb[hbase[b[k]] + off] = make_uint2((unsigned)s[k], (unsigned)d[k]);
        }
    }
}

// fused: per-bucket exact node histogram + dinv + block-local exclusive scan
// (rowptr holds LOCAL offsets after this; part[b] = bucket total)
__global__ void k_nhist_scan(const uint2* __restrict__ eb, const int* __restrict__ bucket_base,
                             int* __restrict__ rowptr, int* __restrict__ part,
                             float* __restrict__ dinv, int n) {
    __shared__ int c[256], sh[256];
    const int tid = threadIdx.x, b = blockIdx.x;
    c[tid] = 0;
    __syncthreads();
    const int beg = bucket_base[b], end = bucket_base[b + 1];
    for (int i = beg + tid; i < end; i += 256)
        atomicAdd(&c[eb[i].y & 255], 1);
    __syncthreads();
    const int v = c[tid];
    const int node = b * 256 + tid;
    if (node < n) dinv[node] = rsqrtf((float)(v + 1));  // deg includes self-loop
    int x = v;
    sh[tid] = x;
    __syncthreads();
    for (int off = 1; off < 256; off <<= 1) {
        const int t = (tid >= off) ? sh[tid - off] : 0;
        __syncthreads();
        if (tid >= off) { x += t; sh[tid] = x; }
        __syncthreads();
    }
    if (node <= n) rowptr[node] = x - v;       // local exclusive offset
    if (tid == 255) part[b] = x;               // bucket total
}

// fused: part-prefix + rowptr globalization + placement.
// PREW: also stores the per-edge premultiplied norm weight (src, f32 bits).
template <bool PREW>
__global__ void k_place(const uint2* __restrict__ eb, const int* __restrict__ bucket_base,
                        int* __restrict__ rowptr, const int* __restrict__ part,
                        void* __restrict__ esv, const float* __restrict__ dinv,
                        int n, int nb) {
    __shared__ int sh[256], rp[256], offs[256];
    __shared__ float sdv[256];
    const int tid = threadIdx.x, b = blockIdx.x;
    // inclusive scan of part[] (196 entries)
    int x = (tid < nb) ? part[tid] : 0;
    sh[tid] = x;
    __syncthreads();
    for (int off = 1; off < 256; off <<= 1) {
        const int t = (tid >= off) ? sh[tid - off] : 0;
        __syncthreads();
        if (tid >= off) { x += t; sh[tid] = x; }
        __syncthreads();
    }
    const int prefix = (b > 0) ? sh[b - 1] : 0;
    const int node = b * 256 + tid;
    int rg = 0;
    if (node <= n) {
        rg = rowptr[node] + prefix;
        rowptr[node] = rg;                     // now global (props read this)
    }
    rp[tid] = rg;
    offs[tid] = 0;
    if (PREW) sdv[tid] = (node < n) ? dinv[node] : 0.f;
    __syncthreads();
    const int beg = bucket_base[b], end = bucket_base[b + 1];
    if (PREW) {
        int2* es2 = (int2*)esv;
        for (int i = beg + tid; i < end; i += 256) {
            const uint2 ed = eb[i];
            const int sI = (int)ed.x, d = (int)ed.y & 255;
            const float w = dinv[sI] * sdv[d];
            const int local = atomicAdd(&offs[d], 1);
            es2[rp[d] + local] = make_int2(sI, __float_as_int(w));
        }
    } else {
        int* es1 = (int*)esv;
        for (int i = beg + tid; i < end; i += 256) {
            const uint2 ed = eb[i];
            const int d = (int)ed.y & 255;
            const int local = atomicAdd(&offs[d], 1);
            es1[rp[d] + local] = (int)ed.x;
        }
    }
}

// ---------------- MFMA GEMM: C[M,Nc] = A[M,256] @ Bt[Nc,256]^T ----------------
// AF32: A is fp32 (cast to bf16 in staging)   FP8OUT: C quantized to fp8 e4m3
#define LP 40
template <bool AF32, bool FP8OUT>
__global__ __launch_bounds__(256) void k_gemm(const void* __restrict__ Av,
                                              const unsigned short* __restrict__ Bt,
                                              void* __restrict__ Cout,
                                              int M, int Nc) {
    __shared__ unsigned short As[128 * LP];
    __shared__ unsigned short Bs[128 * LP];

    const int tid = threadIdx.x;
    const int wave = tid >> 6, lane = tid & 63;
    const int wm = (wave >> 1) * 64, wn = (wave & 1) * 64;
    const int l15 = lane & 15, quad = lane >> 4;
    const int mBase = blockIdx.x * 128, nBase = blockIdx.y * 128;

    f32x4 acc[4][4];
#pragma unroll
    for (int i = 0; i < 4; i++)
#pragma unroll
        for (int j = 0; j < 4; j++) acc[i][j] = (f32x4){0.f, 0.f, 0.f, 0.f};

    const int r0 = tid >> 2, kc0 = tid & 3;       // staged rows r0 and r0+64
    int am0 = mBase + r0;      if (am0 >= M) am0 = M - 1;
    int am1 = mBase + r0 + 64; if (am1 >= M) am1 = M - 1;

    const uint4* Ap0; const uint4* Ap1; const float4* Af0; const float4* Af1;
    if (AF32) {
        Af0 = (const float4*)Av + (size_t)am0 * 64 + kc0 * 2;
        Af1 = (const float4*)Av + (size_t)am1 * 64 + kc0 * 2;
    } else {
        Ap0 = (const uint4*)Av + (size_t)am0 * 32 + kc0;
        Ap1 = (const uint4*)Av + (size_t)am1 * 32 + kc0;
    }
    const uint4* Bp0 = (const uint4*)Bt + (size_t)(nBase + r0) * 32 + kc0;
    const uint4* Bp1 = (const uint4*)Bt + (size_t)(nBase + r0 + 64) * 32 + kc0;

    for (int kt = 0; kt < 8; ++kt) {
        uint4 a0, a1;
        if (AF32) {
            const float4 l0 = Af0[kt * 8], h0 = Af0[kt * 8 + 1];
            const float4 l1 = Af1[kt * 8], h1 = Af1[kt * 8 + 1];
            a0.x = pk_bf16(l0.x, l0.y); a0.y = pk_bf16(l0.z, l0.w);
            a0.z = pk_bf16(h0.x, h0.y); a0.w = pk_bf16(h0.z, h0.w);
            a1.x = pk_bf16(l1.x, l1.y); a1.y = pk_bf16(l1.z, l1.w);
            a1.z = pk_bf16(h1.x, h1.y); a1.w = pk_bf16(h1.z, h1.w);
        } else {
            a0 = Ap0[kt * 4];
            a1 = Ap1[kt * 4];
        }
        const uint4 b0 = Bp0[kt * 4];
        const uint4 b1 = Bp1[kt * 4];
        __syncthreads();
        *(uint4*)&As[r0 * LP + kc0 * 8] = a0;
        *(uint4*)&As[(r0 + 64) * LP + kc0 * 8] = a1;
        *(uint4*)&Bs[r0 * LP + kc0 * 8] = b0;
        *(uint4*)&Bs[(r0 + 64) * LP + kc0 * 8] = b1;
        __syncthreads();

        s16x8 af[4], bf[4];
#pragma unroll
        for (int i = 0; i < 4; i++)
            af[i] = *(const s16x8*)&As[(wm + i * 16 + l15) * LP + quad * 8];
#pragma unroll
        for (int j = 0; j < 4; j++)
            bf[j] = *(const s16x8*)&Bs[(wn + j * 16 + l15) * LP + quad * 8];
#pragma unroll
        for (int i = 0; i < 4; i++)
#pragma unroll
            for (int j = 0; j < 4; j++)
                acc[i][j] = __builtin_amdgcn_mfma_f32_16x16x32_bf16(af[i], bf[j], acc[i][j], 0, 0, 0);
    }

#pragma unroll
    for (int i = 0; i < 4; i++) {
        const int rowb = mBase + wm + i * 16 + quad * 4;
#pragma unroll
        for (int j = 0; j < 4; j++) {
            const int col = nBase + wn + j * 16 + l15;
#pragma unroll
            for (int r = 0; r < 4; r += 2) {
                if (FP8OUT) {
                    const unsigned int pk = __builtin_amdgcn_cvt_pk_fp8_f32(
                        acc[i][j][r], acc[i][j][r + 1], 0, false);
                    if (rowb + r < M)
                        ((unsigned char*)Cout)[(size_t)(rowb + r) * Nc + col] =
                            (unsigned char)pk;
                    if (rowb + r + 1 < M)
                        ((unsigned char*)Cout)[(size_t)(rowb + r + 1) * Nc + col] =
                            (unsigned char)(pk >> 8);
                } else {
                    const unsigned int pk = pk_bf16(acc[i][j][r], acc[i][j][r + 1]);
                    if (rowb + r < M)
                        ((unsigned short*)Cout)[(size_t)(rowb + r) * Nc + col] =
                            (unsigned short)pk;
                    if (rowb + r + 1 < M)
                        ((unsigned short*)Cout)[(size_t)(rowb + r + 1) * Nc + col] =
                            (unsigned short)(pk >> 16);
                }
            }
        }
    }
}

// ---------------- propagation ----------------
// Quarter-wave per edge, 4-deep gather pipeline (4 rows in flight/wave),
// branchless weight-zeroed tail. PREW: edge list carries premultiplied weight.

// L1: 256 feats fp8 = 16 uint4/row. Packed f32x2 accumulate; quad 0 stores H bf16.
template <bool PREW>
__global__ void k_prop256f8(const uint4* __restrict__ X4,
                            const int* __restrict__ rowptr,
                            const void* __restrict__ esv,
                            const float* __restrict__ dinv,
                            const float* __restrict__ bias,
                            uint4* __restrict__ Y4, int n) {
    const int wid = (int)((blockIdx.x * blockDim.x + threadIdx.x) >> 6);
    const int lane = threadIdx.x & 63;
    const int quad = lane >> 4, l16 = lane & 15;
    if (wid >= n) return;
    const float dd = dinv[wid];
    const int2* es2 = (const int2*)esv;
    const int*  es1 = (const int*)esv;
    f32x2 a[8];
#pragma unroll
    for (int k = 0; k < 8; k++) a[k] = (f32x2){0.f, 0.f};

    const int beg = rowptr[wid], end = rowptr[wid + 1];
    int j = beg + quad;

    auto EDGE = [&](int jj, int& s, float& w) {
        const bool v = jj < end;
        const int idx = v ? jj : 0;           // dummy 0 is always safe
        if (PREW) {
            const int2 p = es2[idx];
            s = p.x;
            w = v ? __int_as_float(p.y) : 0.f;
        } else {
            s = es1[idx];
            w = v ? dinv[s] * dd : 0.f;
        }
    };

    int s0, s1, s2, s3;
    float w0, w1, w2, w3;
    EDGE(j, s0, w0); EDGE(j + 4, s1, w1); EDGE(j + 8, s2, w2); EDGE(j + 12, s3, w3);

    // self-loop: only quad 0 loads (exec-masked lanes fetch nothing)
    if (quad == 0) {
        const uint4 v = X4[(size_t)wid * 16 + l16];
        acc16p(a, v, (f32x2){dd * dd, dd * dd});
    }

    while (j + 12 < end) {
        const uint4 u0 = X4[(size_t)s0 * 16 + l16];
        const uint4 u1 = X4[(size_t)s1 * 16 + l16];
        const uint4 u2 = X4[(size_t)s2 * 16 + l16];
        const uint4 u3 = X4[(size_t)s3 * 16 + l16];
        j += 16;
        int t0, t1, t2, t3;
        float x0, x1, x2, x3;
        EDGE(j, t0, x0); EDGE(j + 4, t1, x1); EDGE(j + 8, t2, x2); EDGE(j + 12, t3, x3);
        acc16p(a, u0, (f32x2){w0, w0});
        acc16p(a, u1, (f32x2){w1, w1});
        acc16p(a, u2, (f32x2){w2, w2});
        acc16p(a, u3, (f32x2){w3, w3});
        s0 = t0; s1 = t1; s2 = t2; s3 = t3;
        w0 = x0; w1 = x1; w2 = x2; w3 = x3;
    }
    // tail: <=3 valid entries remain; invalid ones carry w==0 (contribute 0)
    {
        const uint4 u0 = X4[(size_t)s0 * 16 + l16];
        const uint4 u1 = X4[(size_t)s1 * 16 + l16];
        const uint4 u2 = X4[(size_t)s2 * 16 + l16];
        acc16p(a, u0, (f32x2){w0, w0});
        acc16p(a, u1, (f32x2){w1, w1});
        acc16p(a, u2, (f32x2){w2, w2});
    }
#pragma unroll
    for (int k = 0; k < 8; k++) {
        a[k][0] += __shfl_xor(a[k][0], 16);
        a[k][1] += __shfl_xor(a[k][1], 16);
        a[k][0] += __shfl_xor(a[k][0], 32);
        a[k][1] += __shfl_xor(a[k][1], 32);
    }
    if (quad == 0) {
        // feats linear order: a[0].xy, a[1].xy, ..., a[7].xy at base l16*16
        const float4* bp = (const float4*)bias + l16 * 4;
#pragma unroll
        for (int q = 0; q < 4; q++) {
            const float4 b = bp[q];
            a[2 * q][0]     = fmaxf(a[2 * q][0] + b.x, 0.f);
            a[2 * q][1]     = fmaxf(a[2 * q][1] + b.y, 0.f);
            a[2 * q + 1][0] = fmaxf(a[2 * q + 1][0] + b.z, 0.f);
            a[2 * q + 1][1] = fmaxf(a[2 * q + 1][1] + b.w, 0.f);
        }
        uint4 p0, p1;
        p0.x = pk_bf16(a[0][0], a[0][1]);
        p0.y = pk_bf16(a[1][0], a[1][1]);
        p0.z = pk_bf16(a[2][0], a[2][1]);
        p0.w = pk_bf16(a[3][0], a[3][1]);
        p1.x = pk_bf16(a[4][0], a[4][1]);
        p1.y = pk_bf16(a[5][0], a[5][1]);
        p1.z = pk_bf16(a[6][0], a[6][1]);
        p1.w = pk_bf16(a[7][0], a[7][1]);
        Y4[(size_t)wid * 32 + l16 * 2] = p0;
        Y4[(size_t)wid * 32 + l16 * 2 + 1] = p1;
    }
}

// L2: 128 feats bf16 = 16 uint4/row. Packed f32x2 accumulate; quad 0 stores fp32.
template <bool PREW>
__global__ void k_prop128b(const uint4* __restrict__ X4,
                           const int* __restrict__ rowptr,
                           const void* __restrict__ esv,
                           const float* __restrict__ dinv,
                           const float* __restrict__ bias,
                           float* __restrict__ Yout, int n) {
    const int wid = (int)((blockIdx.x * blockDim.x + threadIdx.x) >> 6);
    const int lane = threadIdx.x & 63;
    const int quad = lane >> 4, l16 = lane & 15;
    if (wid >= n) return;
    const float dd = dinv[wid];
    const int2* es2 = (const int2*)esv;
    const int*  es1 = (const int*)esv;
    f32x2 a[4];
#pragma unroll
    for (int k = 0; k < 4; k++) a[k] = (f32x2){0.f, 0.f};

    const int beg = rowptr[wid], end = rowptr[wid + 1];
    int j = beg + quad;

    auto EDGE = [&](int jj, int& s, float& w) {
        const bool v = jj < end;
        const int idx = v ? jj : 0;
        if (PREW) {
            const int2 p = es2[idx];
            s = p.x;
            w = v ? __int_as_float(p.y) : 0.f;
        } else {
            s = es1[idx];
            w = v ? dinv[s] * dd : 0.f;
        }
    };

    int s0, s1, s2, s3;
    float w0, w1, w2, w3;
    EDGE(j, s0, w0); EDGE(j + 4, s1, w1); EDGE(j + 8, s2, w2); EDGE(j + 12, s3, w3);

    if (quad == 0) {
        const uint4 v = X4[(size_t)wid * 16 + l16];
        acc8p(a, v, (f32x2){dd * dd, dd * dd});
    }

    while (j + 12 < end) {
        const uint4 u0 = X4[(size_t)s0 * 16 + l16];
        const uint4 u1 = X4[(size_t)s1 * 16 + l16];
        const uint4 u2 = X4[(size_t)s2 * 16 + l16];
        const uint4 u3 = X4[(size_t)s3 * 16 + l16];
        j += 16;
        int t0, t1, t2, t3;
        float x0, x1, x2, x3;
        EDGE(j, t0, x0); EDGE(j + 4, t1, x1); EDGE(j + 8, t2, x2); EDGE(j + 12, t3, x3);
        acc8p(a, u0, (f32x2){w0, w0});
        acc8p(a, u1, (f32x2){w1, w1});
        acc8p(a, u2, (f32x2){w2, w2});
        acc8p(a, u3, (f32x2){w3, w3});
        s0 = t0; s1 = t1; s2 = t2; s3 = t3;
        w0 = x0; w1 = x1; w2 = x2; w3 = x3;
    }
    {
        const uint4 u0 = X4[(size_t)s0 * 16 + l16];
        const uint4 u1 = X4[(size_t)s1 * 16 + l16];
        const uint4 u2 = X4[(size_t)s2 * 16 + l16];
        acc8p(a, u0, (f32x2){w0, w0});
        acc8p(a, u1, (f32x2){w1, w1});
        acc8p(a, u2, (f32x2){w2, w2});
    }
#pragma unroll
    for (int k = 0; k < 4; k++) {
        a[k][0] += __shfl_xor(a[k][0], 16);
        a[k][1] += __shfl_xor(a[k][1], 16);
        a[k][0] += __shfl_xor(a[k][0], 32);
        a[k][1] += __shfl_xor(a[k][1], 32);
    }
    if (quad == 0) {
        const float4 b0 = ((const float4*)bias)[l16 * 2];
        const float4 b1 = ((const float4*)bias)[l16 * 2 + 1];
        float4* op = (float4*)Yout + (size_t)wid * 32 + l16 * 2;
        op[0] = make_float4(a[0][0] + b0.x, a[0][1] + b0.y, a[1][0] + b0.z, a[1][1] + b0.w);
        op[1] = make_float4(a[2][0] + b1.x, a[2][1] + b1.y, a[3][0] + b1.z, a[3][1] + b1.w);
    }
}

extern "C" void kernel_launch(void* const* d_in, const int* in_sizes, int n_in,
                              void* d_out, int out_size, void* d_ws, size_t ws_size,
                              hipStream_t stream) {
    const float* x  = (const float*)d_in[0];
    const int*   ei = (const int*)d_in[1];
    const float* W1 = (const float*)d_in[2];
    const float* b1 = (const float*)d_in[3];
    const float* W2 = (const float*)d_in[4];
    const float* b2 = (const float*)d_in[5];
    float* out = (float*)d_out;

    const int n = in_sizes[0] / 256;  // 50000
    const int e = in_sizes[1] / 2;    // 1600000
    const int* src = ei;
    const int* dst = ei + e;
    const int nb = (n + 255) >> 8;    // 196 buckets (<=256 required)

    // decide whether the premultiplied-weight edge list (8B/edge) fits
    auto al = [](size_t v) { return (v + 511) & ~(size_t)511; };
    const size_t fixed = al(sizeof(float) * n) + al(sizeof(int) * (n + 1)) +
                         al(1024) + al(1024) + al(sizeof(int) * 257) + al(1024) +
                         al(2ull * 256 * 256) + al(2ull * 128 * 256) +
                         al((size_t)n * 256) + al(2ull * n * 256) + al(2ull * n * 128);
    const bool prew = (fixed + al(8ull * (size_t)e)) <= ws_size;

    char* wsp = (char*)d_ws;
    size_t off = 0;
    auto alloc = [&](size_t bytes) -> char* {
        char* p = wsp + off;
        off += (bytes + 511) & ~(size_t)511;
        return p;
    };
    float* dinv    = (float*)alloc(sizeof(float) * n);
    int*   rowptr  = (int*)alloc(sizeof(int) * (n + 1));
    int*   part    = (int*)alloc(1024);
    int*   bcnt    = (int*)alloc(1024);
    int*   bbase   = (int*)alloc(sizeof(int) * 257);
    int*   bcur    = (int*)alloc(1024);
    void*  es      = (void*)alloc((prew ? 8ull : 4ull) * (size_t)e);
    unsigned short* W1t = (unsigned short*)alloc(2ull * 256 * 256); // [N][K]
    unsigned short* W2t = (unsigned short*)alloc(2ull * 128 * 256); // [N][K]
    unsigned char*  T1  = (unsigned char*)alloc((size_t)n * 256);   // x@W1 fp8
    unsigned short* H   = (unsigned short*)alloc(2ull * n * 256);   // relu(prop+b1) bf16
    unsigned short* T2  = (unsigned short*)alloc(2ull * n * 128);   // H@W2 bf16
    // eb (binned (src,dst) pairs, 8B*e = 12.8MB) aliases H (25.6MB):
    // build finishes (k_place) before H is first written (prop256f8).
    uint2* eb = (uint2*)H;

    const int nb_t = (e + TILE - 1) / TILE;
    const int tw_b = (65536 + 32768) / 256;   // 384 transpose blocks

    // ---- binned CSR build (5 dispatches; weight transpose fused into hist) ----
    (void)hipMemsetAsync(bcnt, 0, sizeof(int) * 256, stream);
    k_bhist_tw<<<nb_t + tw_b, 256, 0, stream>>>(dst, bcnt, e, nb, nb_t, W1, W2, W1t, W2t);
    k_bscan<<<1, 256, 0, stream>>>(bcnt, bbase, bcur, nb, e);
    k_bscatter<<<nb_t, 256, 0, stream>>>(src, dst, bcur, eb, e);
    k_nhist_scan<<<nb, 256, 0, stream>>>(eb, bbase, rowptr, part, dinv, n);
    if (prew)
        k_place<true><<<nb, 256, 0, stream>>>(eb, bbase, rowptr, part, es, dinv, n, nb);
    else
        k_place<false><<<nb, 256, 0, stream>>>(eb, bbase, rowptr, part, es, dinv, n, nb);

    // ---- layer 1: T1 = fp8(x@W1)  (fp32 A cast fused in staging) ----
    dim3 g1((n + 127) / 128, 2);
    k_gemm<true, true><<<g1, 256, 0, stream>>>(x, W1t, T1, n, 256);
    if (prew)
        k_prop256f8<true><<<(n + 3) / 4, 256, 0, stream>>>((const uint4*)T1, rowptr, es,
                                                           dinv, b1, (uint4*)H, n);
    else
        k_prop256f8<false><<<(n + 3) / 4, 256, 0, stream>>>((const uint4*)T1, rowptr, es,
                                                            dinv, b1, (uint4*)H, n);

    // ---- layer 2: T2 = bf16(H@W2); out = prop(T2)+b2 ----
    dim3 g2((n + 127) / 128, 1);
    k_gemm<false, false><<<g2, 256, 0, stream>>>(H, W2t, T2, n, 128);
    if (prew)
        k_prop128b<true><<<(n + 3) / 4, 256, 0, stream>>>((const uint4*)T2, rowptr, es,
                                                          dinv, b2, out, n);
    else
        k_prop128b<false><<<(n + 3) / 4, 256, 0, stream>>>((const uint4*)T2, rowptr, es,
                                                           dinv, b2, out, n);
}